// Round 7
// baseline (627.025 us; speedup 1.0000x reference)
//
#include <hip/hip_runtime.h>
#include <math.h>

#define NFC 32   // feature channels
#define DGC 8    // deformable groups (Cg = 4)

#define CDIV(a, b) (((a) + (b) - 1) / (b))

typedef __attribute__((ext_vector_type(8))) short bf16x8;
typedef __attribute__((ext_vector_type(4))) float f32x4;

__device__ __forceinline__ unsigned short f2bf(float f) {
    unsigned int u = __float_as_uint(f);
    u += 0x7fffu + ((u >> 16) & 1u);          // RNE
    return (unsigned short)(u >> 16);
}
__device__ __forceinline__ float bf2f(unsigned short s) {
    return __uint_as_float((unsigned int)s << 16);
}
__device__ __forceinline__ float bf_lo(unsigned int u) { return __uint_as_float(u << 16); }
__device__ __forceinline__ float bf_hi(unsigned int u) { return __uint_as_float(u & 0xffff0000u); }

// ================= weight prep (merged via gridDim.y) =================
struct Ptr4F { const float* s[4]; };
struct Ptr4U { unsigned short* d[4]; };

// om weight (216,32,3,3) -> B-fragment swizzle (bf16):
// wswz[((t*14+nt)*64 + lane)*8 + j] = w[n=nt*16+(lane&15)][ic=(lane>>4)*8+j][t]
__global__ void k_swz_om4(Ptr4F src, Ptr4U dst) {
    const float* w = src.s[blockIdx.y];
    unsigned short* o = dst.d[blockIdx.y];
    int i = blockIdx.x * 256 + threadIdx.x;   // 9*14*64*8 = 64512
    if (i >= 9 * 14 * 64 * 8) return;
    int j  = i & 7;
    int l  = (i >> 3) & 63;
    int nt = (i >> 9) % 14;
    int t  = i / (14 * 512);
    int n  = nt * 16 + (l & 15);
    int ic = (l >> 4) * 8 + j;
    float v = (n < 216) ? w[((size_t)(n * 32 + ic)) * 9 + t] : 0.f;
    o[i] = f2bf(v);
}

// conv weight (32, ICt, 3,3) -> A-fragment swizzle (bf16), k ordered (t,ck):
// wA[(((t*KC+ck)*2+mt)*64+lane)*8+j] = w[oc=mt*16+(lane&15)][ic=ck*32+(lane>>4)*8+j][t]
template<int ICt>
__global__ void k_swz_wA(Ptr4F src, Ptr4U dst) {
    const int KC = ICt / 32;
    const float* w = src.s[blockIdx.y];
    unsigned short* o = dst.d[blockIdx.y];
    int i = blockIdx.x * 256 + threadIdx.x;   // 9*KC*2*512
    if (i >= 9 * KC * 1024) return;
    int idx = i;
    int j = idx & 7;   idx >>= 3;
    int l = idx & 63;  idx >>= 6;
    int mt = idx & 1;  idx >>= 1;
    int ck = idx % KC; idx /= KC;
    int t = idx;
    int oc = mt * 16 + (l & 15);
    int ic = ck * 32 + (l >> 4) * 8 + j;
    o[i] = f2bf(w[((size_t)(oc * ICt + ic)) * 9 + t]);
}

// main dcn weight (32,32,3,3) -> A-fragment swizzle over k = ic*9+t (matches samp rows):
// wmA[((kc*2+mt)*64 + l)*8 + j] = w[oc=mt*16+(l&15)][k=kc*32+(l>>4)*8+j], ic=k/9, t=k%9
__global__ void k_swz_wmA4(Ptr4F src, Ptr4U dst) {
    const float* w = src.s[blockIdx.y];
    unsigned short* o = dst.d[blockIdx.y];
    int i = blockIdx.x * 256 + threadIdx.x;   // 9*2*64*8 = 9216
    if (i >= 9216) return;
    int j  = i & 7;
    int l  = (i >> 3) & 63;
    int mt = (i >> 9) & 1;
    int kc = i >> 10;                          // 0..8
    int oc = mt * 16 + (l & 15);
    int k  = kc * 32 + (l >> 4) * 8 + j;
    int ic = k / 9, t = k % 9;
    o[i] = f2bf(w[((size_t)(oc * 32 + ic)) * 9 + t]);
}

// NCHW fp32 -> NHWC bf16 (merged y-layers, same HW)
__global__ void k_cvt_nhwc(Ptr4F src, Ptr4U dst, int HW, int Btot) {
    const float* in = src.s[blockIdx.y];
    unsigned short* out = dst.d[blockIdx.y];
    int i = blockIdx.x * 256 + threadIdx.x;   // over Btot*HW*32, c fastest
    if (i >= Btot * HW * 32) return;
    int c = i & 31;
    int pxf = i >> 5;
    int b = pxf / HW;
    int hw = pxf % HW;
    out[i] = f2bf(in[((size_t)(b * 32 + c)) * HW + hw]);
}

// NHWC bf16 (b,h,w,32) -> group-planar xg (b,g,h,w,4) bf16
__global__ void k_cvt_xg(const unsigned short* __restrict__ in,
                         unsigned short* __restrict__ out, int HW, int B) {
    int i = blockIdx.x * 256 + threadIdx.x;   // over B*HW*8, g fastest
    if (i >= B * HW * 8) return;
    int g = i & 7;
    int pxf = i >> 3;
    int b = pxf / HW;
    int hw = pxf % HW;
    uint2 v = *(const uint2*)(in + (size_t)pxf * 32 + g * 4);
    *(uint2*)(out + (((size_t)(b * 8 + g) * HW) + hw) * 4) = v;
}

// ================= MFMA 3x3 conv, NHWC bf16 in/out (+ optional xg copy) =================
template<int NT, int KC, int STRIDE, bool LRELU, bool XG>
__global__ __launch_bounds__(256)
void k_conv_mfma(const unsigned short* __restrict__ in1,  // NHWC bf16 32ch
                 const unsigned short* __restrict__ in2,  // NHWC bf16 32ch (KC=2) or null
                 const unsigned short* __restrict__ wA,   // A-fragment swizzled
                 const float* __restrict__ bias,          // [32]
                 unsigned short* __restrict__ out,        // NHWC bf16 32ch
                 unsigned short* __restrict__ outg,       // xg (b,g,h,w,4) if XG
                 int B, int Hin, int Win, int Hout, int Wout) {
    int wid  = (blockIdx.x * 256 + threadIdx.x) >> 6;
    int lane = threadIdx.x & 63;
    int strips = Wout / (16 * NT);
    if (wid >= B * Hout * strips) return;
    int st = wid % strips;
    int h  = (wid / strips) % Hout;
    int b  = wid / (strips * Hout);
    int px0 = st * 16 * NT;

    f32x4 acc[NT][2];
#pragma unroll
    for (int nt = 0; nt < NT; ++nt)
#pragma unroll
        for (int mt = 0; mt < 2; ++mt)
#pragma unroll
            for (int r = 0; r < 4; ++r) acc[nt][mt][r] = 0.f;

    int n  = lane & 15;
    int kq = lane >> 4;

#pragma unroll
    for (int t = 0; t < 9; ++t) {
        int hy = h * STRIDE + t / 3 - 1;
        if (hy < 0 || hy >= Hin) continue;
#pragma unroll
        for (int ck = 0; ck < KC; ++ck) {
            const unsigned short* rowp =
                ((KC == 2 && ck == 1) ? in2 : in1) + ((size_t)(b * Hin + hy) * Win) * 32;
            bf16x8 a0 = *(const bf16x8*)(wA + (size_t)((((t * KC + ck) * 2 + 0) * 64 + lane)) * 8);
            bf16x8 a1 = *(const bf16x8*)(wA + (size_t)((((t * KC + ck) * 2 + 1) * 64 + lane)) * 8);
#pragma unroll
            for (int nt = 0; nt < NT; ++nt) {
                int wx = (px0 + nt * 16 + n) * STRIDE + t % 3 - 1;
                bf16x8 bf;
#pragma unroll
                for (int j = 0; j < 8; ++j) bf[j] = 0;
                if (wx >= 0 && wx < Win)
                    bf = *(const bf16x8*)(rowp + (size_t)wx * 32 + kq * 8);
                acc[nt][0] = __builtin_amdgcn_mfma_f32_16x16x32_bf16(a0, bf, acc[nt][0], 0, 0, 0);
                acc[nt][1] = __builtin_amdgcn_mfma_f32_16x16x32_bf16(a1, bf, acc[nt][1], 0, 0, 0);
            }
        }
    }

    size_t rowbase = ((size_t)(b * Hout + h) * Wout);
#pragma unroll
    for (int mt = 0; mt < 2; ++mt) {
        float4 bs = *(const float4*)(bias + mt * 16 + kq * 4);
#pragma unroll
        for (int nt = 0; nt < NT; ++nt) {
            int px = px0 + nt * 16 + n;
            float v0 = acc[nt][mt][0] + bs.x;
            float v1 = acc[nt][mt][1] + bs.y;
            float v2 = acc[nt][mt][2] + bs.z;
            float v3 = acc[nt][mt][3] + bs.w;
            if (LRELU) {
                v0 = (v0 >= 0.f) ? v0 : 0.1f * v0;
                v1 = (v1 >= 0.f) ? v1 : 0.1f * v1;
                v2 = (v2 >= 0.f) ? v2 : 0.1f * v2;
                v3 = (v3 >= 0.f) ? v3 : 0.1f * v3;
            }
            ushort4 sv = make_ushort4(f2bf(v0), f2bf(v1), f2bf(v2), f2bf(v3));
            *(ushort4*)(out + (rowbase + px) * 32 + mt * 16 + kq * 4) = sv;
            if (XG) {
                int g = mt * 4 + kq;   // oc quad = one group's 4 channels
                *(ushort4*)(outg + (((size_t)(b * 8 + g) * Hout + h) * Wout + px) * 4) = sv;
            }
        }
    }
}

// ========== fully fused DCN: om GEMM (LDS) + sampling + MFMA main conv ==========
// Block = 256 thr = 32 px. Phase 0: om GEMM -> s_om[216][32]. Phase 1: thread=(px,g)
// sampling from group-planar xg -> s_samp[px][k=ic*9+t]. Phase 2: wave=(mt,nt) MFMA.
// MODE 0: NHWC bf16 no act. MODE 1: NHWC bf16 + lrelu. MODE 2: NCHW fp32 + lrelu.
template<int MODE>
__global__ __launch_bounds__(256)
void k_dcn_fused(const unsigned short* __restrict__ offn, // (B,H,W,32) bf16
                 const unsigned short* __restrict__ wswz, // om w B-frag swizzled
                 const float* __restrict__ om_b,          // [216]
                 const unsigned short* __restrict__ xg,   // (B,8,H,W,4) bf16 group-planar
                 const unsigned short* __restrict__ wmA,  // main w A-frag swizzled
                 const float* __restrict__ bias,          // [32]
                 float* __restrict__ outf,                // MODE 2
                 unsigned short* __restrict__ outb,       // MODE 0/1
                 int B, int H, int W) {
    const int ROW = 296;   // s_samp row stride (288 + 8 pad)
    const int OMR = 32;    // s_om row stride = 32 px exactly (conflict-free reads)
    __shared__ __align__(16) unsigned short s_om[216 * OMR];   // 13824 B
    __shared__ __align__(16) unsigned short s_samp[32 * ROW];  // 18944 B

    int tid = threadIdx.x;
    int lane = tid & 63;
    int wv = tid >> 6;
    int px0 = blockIdx.x * 32;

    // ---- phase 0: om GEMM into s_om ----
    {
        int n  = lane & 15;
        int kq = lane >> 4;

        int bmt[2], hmt[2], wmt[2];
#pragma unroll
        for (int mt = 0; mt < 2; ++mt) {
            int p0 = px0 + mt * 16;
            bmt[mt] = p0 / (H * W);
            hmt[mt] = (p0 / W) % H;
            wmt[mt] = p0 % W;
        }

        f32x4 acc[4][2];
#pragma unroll
        for (int i = 0; i < 4; ++i)
#pragma unroll
            for (int mt = 0; mt < 2; ++mt)
#pragma unroll
                for (int r = 0; r < 4; ++r) acc[i][mt][r] = 0.f;

#pragma unroll
        for (int t = 0; t < 9; ++t) {
            bf16x8 a[2];
#pragma unroll
            for (int mt = 0; mt < 2; ++mt) {
#pragma unroll
                for (int j = 0; j < 8; ++j) a[mt][j] = 0;
                int hy = hmt[mt] + t / 3 - 1;
                int wx = wmt[mt] + n + t % 3 - 1;
                if (hy >= 0 && hy < H && wx >= 0 && wx < W)
                    a[mt] = *(const bf16x8*)(offn +
                        (((size_t)(bmt[mt] * H + hy) * W + wx) << 5) + kq * 8);
            }
#pragma unroll
            for (int i = 0; i < 4; ++i) {
                int nt = wv * 4 + i;
                if (nt < 14) {
                    bf16x8 bf = *(const bf16x8*)(wswz + (((size_t)t * 14 + nt) * 64 + lane) * 8);
                    acc[i][0] = __builtin_amdgcn_mfma_f32_16x16x32_bf16(a[0], bf, acc[i][0], 0, 0, 0);
                    acc[i][1] = __builtin_amdgcn_mfma_f32_16x16x32_bf16(a[1], bf, acc[i][1], 0, 0, 0);
                }
            }
        }

#pragma unroll
        for (int i = 0; i < 4; ++i) {
            int nt = wv * 4 + i;
            if (nt < 14) {
                int ch = nt * 16 + n;
                if (ch < 216) {
#pragma unroll
                    for (int mt = 0; mt < 2; ++mt) {
                        ushort4 v = make_ushort4(f2bf(acc[i][mt][0]), f2bf(acc[i][mt][1]),
                                                 f2bf(acc[i][mt][2]), f2bf(acc[i][mt][3]));
                        *(ushort4*)(s_om + ch * OMR + mt * 16 + kq * 4) = v;
                    }
                }
            }
        }
    }
    __syncthreads();

    // ---- phase 1: sampling for (px, g) from group-planar xg ----
    {
        int px = tid & 31, g = tid >> 5;
        int idx = px0 + px;
        int w = idx % W;
        int h = (idx / W) % H;
        int b = idx / (W * H);

        float om27[27];
#pragma unroll
        for (int j = 0; j < 27; ++j)
            om27[j] = bf2f(s_om[(g * 27 + j) * OMR + px]) + om_b[g * 27 + j];

        const unsigned short* xb = xg + ((size_t)(b * 8 + g) * H * W) * 4;
        float Hm1 = (float)(H - 1);
        unsigned short arr[36];   // [c][t], k = g*36 + c*9 + t

#pragma unroll
        for (int k = 0; k < 9; ++k) {
            float mval = 1.f / (1.f + __expf(-om27[18 + k]));
            float py  = om27[k]     + (float)(h + k / 3 - 1);
            float pxx = om27[9 + k] + (float)(w + k % 3 - 1);
            float y0f = floorf(py), x0f = floorf(pxx);
            float dy = py - y0f, dx = pxx - x0f;
            int iy0 = (int)y0f, ix0 = (int)x0f;

            float vy0 = (y0f >= 0.f && y0f <= Hm1) ? 1.f : 0.f;
            float vy1 = (y0f + 1.f >= 0.f && y0f + 1.f <= Hm1) ? 1.f : 0.f;
            float vx0 = (ix0 >= 0 && ix0 <= W - 1) ? 1.f : 0.f;
            float vx1 = (ix0 + 1 >= 0 && ix0 + 1 <= W - 1) ? 1.f : 0.f;
            float wx0 = (1.f - dx) * vx0;
            float wx1 = dx * vx1;
            float wy0 = (1.f - dy) * vy0 * mval;
            float wy1 = dy * vy1 * mval;

            int y0c = min(max(iy0, 0), H - 1);
            int y1c = min(max(iy0 + 1, 0), H - 1);
            int bx  = min(max(ix0, 0), W - 2);

            // two x-corners x 4 channels = 16B contiguous per row
            const unsigned short* r0p = xb + ((size_t)y0c * W + bx) * 4;
            const unsigned short* r1p = xb + ((size_t)y1c * W + bx) * 4;
            uint2 a0 = *(const uint2*)r0p;        // x = bx   (ch 0..3)
            uint2 b0 = *(const uint2*)(r0p + 4);  // x = bx+1 (ch 0..3)
            uint2 a1 = *(const uint2*)r1p;
            uint2 b1 = *(const uint2*)(r1p + 4);

            // map loaded pair -> value at x0c / x1c (border-clamp equivalence)
            bool hi0 = (ix0 >= W - 1);   // x0c == bx+1
            bool lo1 = (ix0 < 0);        // x1c == bx
            uint2 sx0r0 = hi0 ? b0 : a0;
            uint2 sx1r0 = lo1 ? a0 : b0;
            uint2 sx0r1 = hi0 ? b1 : a1;
            uint2 sx1r1 = lo1 ? a1 : b1;

#pragma unroll
            for (int c = 0; c < 4; ++c) {
                float v00 = (c & 1) ? bf_hi(((const unsigned int*)&sx0r0)[c >> 1])
                                    : bf_lo(((const unsigned int*)&sx0r0)[c >> 1]);
                float v01 = (c & 1) ? bf_hi(((const unsigned int*)&sx1r0)[c >> 1])
                                    : bf_lo(((const unsigned int*)&sx1r0)[c >> 1]);
                float v10 = (c & 1) ? bf_hi(((const unsigned int*)&sx0r1)[c >> 1])
                                    : bf_lo(((const unsigned int*)&sx0r1)[c >> 1]);
                float v11 = (c & 1) ? bf_hi(((const unsigned int*)&sx1r1)[c >> 1])
                                    : bf_lo(((const unsigned int*)&sx1r1)[c >> 1]);
                float r0 = wx0 * v00 + wx1 * v01;
                float r1 = wx0 * v10 + wx1 * v11;
                arr[c * 9 + k] = f2bf(wy0 * r0 + wy1 * r1);
            }
        }
        ushort4* dst = (ushort4*)(s_samp + px * ROW + g * 36);
        const ushort4* srcp = (const ushort4*)arr;
#pragma unroll
        for (int q = 0; q < 9; ++q) dst[q] = srcp[q];
    }
    __syncthreads();

    // ---- phase 2: wave (mt, nt) computes D[oc 16][px 16] ----
    int wsid = tid >> 6;
    int mt = wsid & 1, nt2 = wsid >> 1;

    f32x4 acc;
#pragma unroll
    for (int r = 0; r < 4; ++r) acc[r] = 0.f;

    const unsigned short* sb = s_samp + (nt2 * 16 + (lane & 15)) * ROW + (lane >> 4) * 8;
#pragma unroll
    for (int kc = 0; kc < 9; ++kc) {
        bf16x8 a   = *(const bf16x8*)(wmA + ((size_t)(kc * 2 + mt) * 64 + lane) * 8);
        bf16x8 bfr = *(const bf16x8*)(sb + kc * 32);
        acc = __builtin_amdgcn_mfma_f32_16x16x32_bf16(a, bfr, acc, 0, 0, 0);
    }

    int pxg = px0 + nt2 * 16 + (lane & 15);
    int kq = lane >> 4;
    float4 bs = *(const float4*)(bias + mt * 16 + kq * 4);
    float v[4] = {acc[0] + bs.x, acc[1] + bs.y, acc[2] + bs.z, acc[3] + bs.w};
    if (MODE >= 1) {
#pragma unroll
        for (int r = 0; r < 4; ++r) v[r] = (v[r] >= 0.f) ? v[r] : 0.1f * v[r];
    }
    if (MODE == 2) {
        int w2 = pxg % W, h2 = (pxg / W) % H, b2 = pxg / (W * H);
#pragma unroll
        for (int r = 0; r < 4; ++r) {
            int oc = mt * 16 + kq * 4 + r;
            outf[((size_t)(b2 * 32 + oc) * H + h2) * W + w2] = v[r];
        }
    } else {
        ushort4 sv = make_ushort4(f2bf(v[0]), f2bf(v[1]), f2bf(v[2]), f2bf(v[3]));
        *(ushort4*)(outb + (size_t)pxg * 32 + mt * 16 + kq * 4) = sv;
    }
}

// ================= exact 2x bilinear upsample, NHWC bf16 =================
__global__ void k_resize2x_nhwc(const unsigned short* __restrict__ in,
                                unsigned short* __restrict__ out,
                                int B, int Hin, int Win) {
    int Hout = Hin * 2, Wout = Win * 2;
    int i = blockIdx.x * 256 + threadIdx.x;     // (b,ho,wo,q) q=ch-octet
    int total = B * Hout * Wout * 4;
    if (i >= total) return;
    int q  = i & 3;
    int wo = (i >> 2) % Wout;
    int ho = (i >> 2) / Wout % Hout;
    int b  = (i >> 2) / (Wout * Hout);
    float fy = 0.5f * (float)ho - 0.25f;
    float fx = 0.5f * (float)wo - 0.25f;
    float y0f = floorf(fy), x0f = floorf(fx);
    float wy1 = fy - y0f, wx1 = fx - x0f;
    int y0 = max(0, min((int)y0f, Hin - 1));
    int y1 = max(0, min((int)y0f + 1, Hin - 1));
    int x0 = max(0, min((int)x0f, Win - 1));
    int x1 = max(0, min((int)x0f + 1, Win - 1));
    const unsigned short* base = in + ((size_t)b * Hin * Win) * 32 + q * 8;
    const uint4 u00 = *(const uint4*)(base + ((size_t)y0 * Win + x0) * 32);
    const uint4 u01 = *(const uint4*)(base + ((size_t)y0 * Win + x1) * 32);
    const uint4 u10 = *(const uint4*)(base + ((size_t)y1 * Win + x0) * 32);
    const uint4 u11 = *(const uint4*)(base + ((size_t)y1 * Win + x1) * 32);
    float c00 = (1.f - wy1) * (1.f - wx1), c01 = (1.f - wy1) * wx1;
    float c10 = wy1 * (1.f - wx1), c11 = wy1 * wx1;
    const unsigned int* p00 = (const unsigned int*)&u00;
    const unsigned int* p01 = (const unsigned int*)&u01;
    const unsigned int* p10 = (const unsigned int*)&u10;
    const unsigned int* p11 = (const unsigned int*)&u11;
    unsigned int packed[4];
#pragma unroll
    for (int d = 0; d < 4; ++d) {
        float lo = c00 * bf_lo(p00[d]) + c01 * bf_lo(p01[d]) +
                   c10 * bf_lo(p10[d]) + c11 * bf_lo(p11[d]);
        float hi = c00 * bf_hi(p00[d]) + c01 * bf_hi(p01[d]) +
                   c10 * bf_hi(p10[d]) + c11 * bf_hi(p11[d]);
        packed[d] = (unsigned int)f2bf(lo) | ((unsigned int)f2bf(hi) << 16);
    }
    *(uint4*)(out + ((size_t)(b * Hout + ho) * Wout + wo) * 32 + q * 8) =
        make_uint4(packed[0], packed[1], packed[2], packed[3]);
}

extern "C" void kernel_launch(void* const* d_in, const int* in_sizes, int n_in,
                              void* d_out, int out_size, void* d_ws, size_t ws_size,
                              hipStream_t stream) {
    const float* L1_fea = (const float*)d_in[0];
    const float* L1_off = (const float*)d_in[1];
    const float* L2_off = (const float*)d_in[2];
    const float* L3_off = (const float*)d_in[3];
    const float* offset = (const float*)d_in[4];
    const float* w_l2c1 = (const float*)d_in[5];   const float* b_l2c1 = (const float*)d_in[6];
    const float* w_l2c2 = (const float*)d_in[7];   const float* b_l2c2 = (const float*)d_in[8];
    const float* w_l3c1 = (const float*)d_in[9];   const float* b_l3c1 = (const float*)d_in[10];
    const float* w_l3c2 = (const float*)d_in[11];  const float* b_l3c2 = (const float*)d_in[12];
    const float* w_l2fea = (const float*)d_in[13]; const float* b_l2fea = (const float*)d_in[14];
    const float* w_l1fea = (const float*)d_in[15]; const float* b_l1fea = (const float*)d_in[16];
    const float* l3_om_w = (const float*)d_in[17]; const float* l3_om_b = (const float*)d_in[18];
    const float* l3_w = (const float*)d_in[19];    const float* l3_b = (const float*)d_in[20];
    const float* l2_om_w = (const float*)d_in[21]; const float* l2_om_b = (const float*)d_in[22];
    const float* l2_w = (const float*)d_in[23];    const float* l2_b = (const float*)d_in[24];
    const float* l1_om_w = (const float*)d_in[25]; const float* l1_om_b = (const float*)d_in[26];
    const float* l1_w = (const float*)d_in[27];    const float* l1_b = (const float*)d_in[28];
    const float* cas_om_w = (const float*)d_in[29]; const float* cas_om_b = (const float*)d_in[30];
    const float* cas_w = (const float*)d_in[31];   const float* cas_b = (const float*)d_in[32];

    const int B = 4, H1 = 192, W1 = 192, H2 = 96, W2 = 96, H3 = 48, W3 = 48;
    const int HW1 = H1 * W1, HW2 = H2 * W2, HW3 = H3 * W3;

    char* ws = (char*)d_ws;
    size_t cur = 0;
    auto alloc = [&](size_t bytes) {
        char* p = ws + cur;
        cur += (bytes + 255) & ~(size_t)255;
        return p;
    };

    // weight buffers
    unsigned short* wA_l2c1  = (unsigned short*)alloc(9216 * 2);
    unsigned short* wA_l2c2  = (unsigned short*)alloc(9216 * 2);
    unsigned short* wA_l3c1  = (unsigned short*)alloc(9216 * 2);
    unsigned short* wA_l3c2  = (unsigned short*)alloc(9216 * 2);
    unsigned short* wA_l2fea = (unsigned short*)alloc(18432 * 2);
    unsigned short* wA_l1fea = (unsigned short*)alloc(18432 * 2);
    unsigned short* wmA_l3   = (unsigned short*)alloc(9216 * 2);
    unsigned short* wmA_l2   = (unsigned short*)alloc(9216 * 2);
    unsigned short* wmA_l1   = (unsigned short*)alloc(9216 * 2);
    unsigned short* wmA_cas  = (unsigned short*)alloc(9216 * 2);
    unsigned short* wswz_l3  = (unsigned short*)alloc(64512 * 2);
    unsigned short* wswz_l2  = (unsigned short*)alloc(64512 * 2);
    unsigned short* wswz_l1  = (unsigned short*)alloc(64512 * 2);
    unsigned short* wswz_cas = (unsigned short*)alloc(64512 * 2);

    // activations (NHWC bf16 + group-planar xg)
    unsigned short* offn_l3  = (unsigned short*)alloc((size_t)B * 32 * HW3 * 2);
    unsigned short* offn_l2  = (unsigned short*)alloc((size_t)B * 32 * HW2 * 2);
    unsigned short* offn_l1  = (unsigned short*)alloc((size_t)B * 32 * HW1 * 2);
    unsigned short* offn_cas = (unsigned short*)alloc((size_t)B * 32 * HW1 * 2);
    unsigned short* xn_l1    = (unsigned short*)alloc((size_t)B * 32 * HW1 * 2);
    unsigned short* L1g      = (unsigned short*)alloc((size_t)B * 32 * HW1 * 2);
    unsigned short* L2a      = (unsigned short*)alloc((size_t)B * 32 * HW2 * 2);
    unsigned short* L2n      = (unsigned short*)alloc((size_t)B * 32 * HW2 * 2);
    unsigned short* L2g      = (unsigned short*)alloc((size_t)B * 32 * HW2 * 2);
    unsigned short* L3a      = (unsigned short*)alloc((size_t)B * 32 * HW3 * 2);
    unsigned short* L3n      = (unsigned short*)alloc((size_t)B * 32 * HW3 * 2);
    unsigned short* L3g      = (unsigned short*)alloc((size_t)B * 32 * HW3 * 2);
    unsigned short* L3f      = (unsigned short*)alloc((size_t)B * 32 * HW3 * 2);
    unsigned short* L2f_pre  = (unsigned short*)alloc((size_t)B * 32 * HW2 * 2);
    unsigned short* L3u      = (unsigned short*)alloc((size_t)B * 32 * HW2 * 2);
    unsigned short* L2f      = (unsigned short*)alloc((size_t)B * 32 * HW2 * 2);
    unsigned short* L1f_pre  = (unsigned short*)alloc((size_t)B * 32 * HW1 * 2);
    unsigned short* L2u      = (unsigned short*)alloc((size_t)B * 32 * HW1 * 2);
    unsigned short* L1f      = (unsigned short*)alloc((size_t)B * 32 * HW1 * 2);
    unsigned short* L1fg     = (unsigned short*)alloc((size_t)B * 32 * HW1 * 2);

    // ---- weight prep (merged) ----
    {
        Ptr4F s = {{l3_om_w, l2_om_w, l1_om_w, cas_om_w}};
        Ptr4U d = {{wswz_l3, wswz_l2, wswz_l1, wswz_cas}};
        k_swz_om4<<<dim3(CDIV(64512, 256), 4), 256, 0, stream>>>(s, d);
    }
    {
        Ptr4F s = {{w_l2c1, w_l2c2, w_l3c1, w_l3c2}};
        Ptr4U d = {{wA_l2c1, wA_l2c2, wA_l3c1, wA_l3c2}};
        k_swz_wA<32><<<dim3(CDIV(9216, 256), 4), 256, 0, stream>>>(s, d);
    }
    {
        Ptr4F s = {{w_l2fea, w_l1fea, nullptr, nullptr}};
        Ptr4U d = {{wA_l2fea, wA_l1fea, nullptr, nullptr}};
        k_swz_wA<64><<<dim3(CDIV(18432, 256), 2), 256, 0, stream>>>(s, d);
    }
    {
        Ptr4F s = {{l3_w, l2_w, l1_w, cas_w}};
        Ptr4U d = {{wmA_l3, wmA_l2, wmA_l1, wmA_cas}};
        k_swz_wmA4<<<dim3(CDIV(9216, 256), 4), 256, 0, stream>>>(s, d);
    }

    // ---- input conversions ----
    {
        Ptr4F s = {{L1_off, offset, L1_fea, nullptr}};
        Ptr4U d = {{offn_l1, offn_cas, xn_l1, nullptr}};
        k_cvt_nhwc<<<dim3(CDIV(B * 32 * HW1, 256), 3), 256, 0, stream>>>(s, d, HW1, B);
    }
    {
        Ptr4F s = {{L2_off, nullptr, nullptr, nullptr}};
        Ptr4U d = {{offn_l2, nullptr, nullptr, nullptr}};
        k_cvt_nhwc<<<dim3(CDIV(B * 32 * HW2, 256), 1), 256, 0, stream>>>(s, d, HW2, B);
    }
    {
        Ptr4F s = {{L3_off, nullptr, nullptr, nullptr}};
        Ptr4U d = {{offn_l3, nullptr, nullptr, nullptr}};
        k_cvt_nhwc<<<dim3(CDIV(B * 32 * HW3, 256), 1), 256, 0, stream>>>(s, d, HW3, B);
    }
    k_cvt_xg<<<CDIV(B * HW1 * 8, 256), 256, 0, stream>>>(xn_l1, L1g, HW1, B);

    // ---- feature pyramid (MFMA convs, NHWC bf16) ----
    k_conv_mfma<3, 1, 2, true, false><<<CDIV(B * H2 * 2, 4), 256, 0, stream>>>(
        xn_l1, nullptr, wA_l2c1, b_l2c1, L2a, nullptr, B, H1, W1, H2, W2);
    k_conv_mfma<3, 1, 1, true, true><<<CDIV(B * H2 * 2, 4), 256, 0, stream>>>(
        L2a, nullptr, wA_l2c2, b_l2c2, L2n, L2g, B, H2, W2, H2, W2);
    k_conv_mfma<3, 1, 2, true, false><<<CDIV(B * H3 * 1, 4), 256, 0, stream>>>(
        L2n, nullptr, wA_l3c1, b_l3c1, L3a, nullptr, B, H2, W2, H3, W3);
    k_conv_mfma<3, 1, 1, true, true><<<CDIV(B * H3 * 1, 4), 256, 0, stream>>>(
        L3a, nullptr, wA_l3c2, b_l3c2, L3n, L3g, B, H3, W3, H3, W3);

    // ---- L3 dcn + lrelu ----
    k_dcn_fused<1><<<B * HW3 / 32, 256, 0, stream>>>(
        offn_l3, wswz_l3, l3_om_b, L3g, wmA_l3, l3_b, nullptr, L3f, B, H3, W3);

    // ---- L2 dcn, upsample L3f, fuse ----
    k_dcn_fused<0><<<B * HW2 / 32, 256, 0, stream>>>(
        offn_l2, wswz_l2, l2_om_b, L2g, wmA_l2, l2_b, nullptr, L2f_pre, B, H2, W2);
    k_resize2x_nhwc<<<CDIV(B * HW2 * 4, 256), 256, 0, stream>>>(L3f, L3u, B, H3, W3);
    k_conv_mfma<3, 2, 1, true, false><<<CDIV(B * H2 * 2, 4), 256, 0, stream>>>(
        L2f_pre, L3u, wA_l2fea, b_l2fea, L2f, nullptr, B, H2, W2, H2, W2);

    // ---- L1 dcn, upsample L2f, fuse (no act) ----
    k_dcn_fused<0><<<B * HW1 / 32, 256, 0, stream>>>(
        offn_l1, wswz_l1, l1_om_b, L1g, wmA_l1, l1_b, nullptr, L1f_pre, B, H1, W1);
    k_resize2x_nhwc<<<CDIV(B * HW1 * 4, 256), 256, 0, stream>>>(L2f, L2u, B, H2, W2);
    k_conv_mfma<4, 2, 1, false, true><<<CDIV(B * H1 * 3, 4), 256, 0, stream>>>(
        L1f_pre, L2u, wA_l1fea, b_l1fea, L1f, L1fg, B, H1, W1, H1, W1);

    // ---- cascading dcn + lrelu -> output (fp32 NCHW) ----
    k_dcn_fused<2><<<B * HW1 / 32, 256, 0, stream>>>(
        offn_cas, wswz_cas, cas_om_b, L1fg, wmA_cas, cas_b, (float*)d_out, nullptr, B, H1, W1);
}

// Round 8
// 532.802 us; speedup vs baseline: 1.1768x; 1.1768x over previous
//
#include <hip/hip_runtime.h>
#include <hip/hip_bf16.h>
#include <math.h>

#define NFC 32   // feature channels
#define DGC 8    // deformable groups (Cg = 4)

#define CDIV(a, b) (((a) + (b) - 1) / (b))

typedef __attribute__((ext_vector_type(8))) short bf16x8;
typedef __attribute__((ext_vector_type(4))) float f32x4;
typedef __attribute__((ext_vector_type(2))) float f32x2;

__device__ __forceinline__ unsigned short f2bf(float f) {
    unsigned int u = __float_as_uint(f);
    u += 0x7fffu + ((u >> 16) & 1u);          // RNE
    return (unsigned short)(u >> 16);
}
__device__ __forceinline__ float bf2f(unsigned short s) {
    return __uint_as_float((unsigned int)s << 16);
}
__device__ __forceinline__ float bf_lo(unsigned int u) { return __uint_as_float(u << 16); }
__device__ __forceinline__ float bf_hi(unsigned int u) { return __uint_as_float(u & 0xffff0000u); }

// packed f32x2 -> bf16x2 (v_cvt_pk_bf16_f32 on gfx950), RNE
__device__ __forceinline__ unsigned int pkbf(float a, float b) {
    __hip_bfloat162 h = __float22bfloat162_rn(make_float2(a, b));
    union { __hip_bfloat162 h2; unsigned int u; } cv;
    cv.h2 = h;
    return cv.u;
}

// ================= merged weight prep =================
struct PrepP {
    const float* om_w[4]; unsigned short* wswz[4];   // y 0..3
    const float* cw[4];   unsigned short* wA[4];     // y 4..7  (32-ic convs)
    const float* cw2[2];  unsigned short* wA2[2];    // y 8..9  (64-ic convs)
    const float* mw[4];   unsigned short* wmA[4];    // y 10..13
};

__global__ void k_prep(PrepP p) {
    int y = blockIdx.y;
    int i = blockIdx.x * 256 + threadIdx.x;
    if (y < 4) {
        // om weight (216,32,3,3) -> B-frag: wswz[((t*14+nt)*64+l)*8+j] = w[n][ic][t]
        if (i >= 9 * 14 * 64 * 8) return;
        int j  = i & 7;
        int l  = (i >> 3) & 63;
        int nt = (i >> 9) % 14;
        int t  = i / (14 * 512);
        int n  = nt * 16 + (l & 15);
        int ic = (l >> 4) * 8 + j;
        float v = (n < 216) ? p.om_w[y][(n * 32 + ic) * 9 + t] : 0.f;
        p.wswz[y][i] = f2bf(v);
    } else if (y < 8) {
        // conv w (32,32,3,3) -> A-frag k=(t,ck): wA[(((t)*2+mt)*64+l)*8+j]
        if (i >= 9 * 1024) return;
        int idx = i;
        int j = idx & 7;   idx >>= 3;
        int l = idx & 63;  idx >>= 6;
        int mt = idx & 1;  idx >>= 1;
        int t = idx;
        int oc = mt * 16 + (l & 15);
        int ic = (l >> 4) * 8 + j;
        p.wA[y - 4][i] = f2bf(p.cw[y - 4][(oc * 32 + ic) * 9 + t]);
    } else if (y < 10) {
        // conv w (32,64,3,3) -> A-frag k=(t,ck)
        if (i >= 9 * 2 * 1024) return;
        int idx = i;
        int j = idx & 7;   idx >>= 3;
        int l = idx & 63;  idx >>= 6;
        int mt = idx & 1;  idx >>= 1;
        int ck = idx & 1;  idx >>= 1;
        int t = idx;
        int oc = mt * 16 + (l & 15);
        int ic = ck * 32 + (l >> 4) * 8 + j;
        p.wA2[y - 8][i] = f2bf(p.cw2[y - 8][(oc * 64 + ic) * 9 + t]);
    } else {
        // main dcn w (32,32,3,3) -> A-frag over k_new = g*36 + t*4 + c
        if (i >= 9216) return;
        int j  = i & 7;
        int l  = (i >> 3) & 63;
        int mt = (i >> 9) & 1;
        int kc = i >> 10;                          // 0..8
        int oc = mt * 16 + (l & 15);
        int k  = kc * 32 + (l >> 4) * 8 + j;       // k_new
        int g = k / 36, r = k % 36, t = r >> 2, c = r & 3;
        p.wmA[y - 10][i] = f2bf(p.mw[y - 10][(oc * 32 + g * 4 + c) * 9 + t]);
    }
}

// ================= merged input conversion =================
// mode 0: NCHW fp32 -> NHWC bf16 ; mode 1: NCHW fp32 -> group-planar xg (b,g,h,w,4) bf16
struct CvtP { const float* src[6]; unsigned short* dst[6]; int HW[6]; int mode[6]; };

__global__ void k_cvt(CvtP p) {
    int y = blockIdx.y;
    int HW = p.HW[y];
    int i = blockIdx.x * 256 + threadIdx.x;
    if (p.mode[y] == 0) {
        if (i >= 4 * HW * 32) return;
        int c = i & 31;
        int pxf = i >> 5;
        int b = pxf / HW;
        int hw = pxf % HW;
        p.dst[y][i] = f2bf(p.src[y][(b * 32 + c) * HW + hw]);
    } else {
        if (i >= 4 * 8 * HW) return;
        int hw = i % HW;
        int bg = i / HW;               // b*8+g
        int b = bg >> 3, g = bg & 7;
        const float* s = p.src[y] + (b * 32 + g * 4) * HW + hw;
        unsigned int lo = pkbf(s[0], s[HW]);
        unsigned int hi = pkbf(s[2 * HW], s[3 * HW]);
        *(uint2*)(p.dst[y] + (size_t)(bg * HW + hw) * 4) = make_uint2(lo, hi);
    }
}

// ================= MFMA 3x3 conv, NHWC bf16 in/out (+ optional xg copy) =================
template<int NT, int KC, int STRIDE, bool LRELU, bool XG>
__global__ __launch_bounds__(256)
void k_conv_mfma(const unsigned short* __restrict__ in1,  // NHWC bf16 32ch
                 const unsigned short* __restrict__ in2,  // NHWC bf16 32ch (KC=2) or null
                 const unsigned short* __restrict__ wA,   // A-fragment swizzled
                 const float* __restrict__ bias,          // [32]
                 unsigned short* __restrict__ out,        // NHWC bf16 32ch
                 unsigned short* __restrict__ outg,       // xg (b,g,h,w,4) if XG
                 int B, int Hin, int Win, int Hout, int Wout) {
    int wid  = (blockIdx.x * 256 + threadIdx.x) >> 6;
    int lane = threadIdx.x & 63;
    int strips = Wout / (16 * NT);
    if (wid >= B * Hout * strips) return;
    int st = wid % strips;
    int h  = (wid / strips) % Hout;
    int b  = wid / (strips * Hout);
    int px0 = st * 16 * NT;

    f32x4 acc[NT][2];
#pragma unroll
    for (int nt = 0; nt < NT; ++nt)
#pragma unroll
        for (int mt = 0; mt < 2; ++mt)
#pragma unroll
            for (int r = 0; r < 4; ++r) acc[nt][mt][r] = 0.f;

    int n  = lane & 15;
    int kq = lane >> 4;

#pragma unroll
    for (int t = 0; t < 9; ++t) {
        int hy = h * STRIDE + t / 3 - 1;
        if (hy < 0 || hy >= Hin) continue;
#pragma unroll
        for (int ck = 0; ck < KC; ++ck) {
            const unsigned short* rowp =
                ((KC == 2 && ck == 1) ? in2 : in1) + (size_t)(b * Hin + hy) * Win * 32;
            bf16x8 a0 = *(const bf16x8*)(wA + ((((t * KC + ck) * 2 + 0) * 64 + lane)) * 8);
            bf16x8 a1 = *(const bf16x8*)(wA + ((((t * KC + ck) * 2 + 1) * 64 + lane)) * 8);
#pragma unroll
            for (int nt = 0; nt < NT; ++nt) {
                int wx = (px0 + nt * 16 + n) * STRIDE + t % 3 - 1;
                bf16x8 bf;
#pragma unroll
                for (int j = 0; j < 8; ++j) bf[j] = 0;
                if (wx >= 0 && wx < Win)
                    bf = *(const bf16x8*)(rowp + wx * 32 + kq * 8);
                acc[nt][0] = __builtin_amdgcn_mfma_f32_16x16x32_bf16(a0, bf, acc[nt][0], 0, 0, 0);
                acc[nt][1] = __builtin_amdgcn_mfma_f32_16x16x32_bf16(a1, bf, acc[nt][1], 0, 0, 0);
            }
        }
    }

    size_t rowbase = ((size_t)(b * Hout + h) * Wout);
#pragma unroll
    for (int mt = 0; mt < 2; ++mt) {
        float4 bs = *(const float4*)(bias + mt * 16 + kq * 4);
#pragma unroll
        for (int nt = 0; nt < NT; ++nt) {
            int px = px0 + nt * 16 + n;
            float v0 = acc[nt][mt][0] + bs.x;
            float v1 = acc[nt][mt][1] + bs.y;
            float v2 = acc[nt][mt][2] + bs.z;
            float v3 = acc[nt][mt][3] + bs.w;
            if (LRELU) {
                v0 = (v0 >= 0.f) ? v0 : 0.1f * v0;
                v1 = (v1 >= 0.f) ? v1 : 0.1f * v1;
                v2 = (v2 >= 0.f) ? v2 : 0.1f * v2;
                v3 = (v3 >= 0.f) ? v3 : 0.1f * v3;
            }
            uint2 sv = make_uint2(pkbf(v0, v1), pkbf(v2, v3));
            *(uint2*)(out + (rowbase + px) * 32 + mt * 16 + kq * 4) = sv;
            if (XG) {
                int g = mt * 4 + kq;   // oc quad = one group's 4 channels
                *(uint2*)(outg + (((size_t)(b * 8 + g) * Hout + h) * Wout + px) * 4) = sv;
            }
        }
    }
}

// ========== fully fused DCN: om GEMM (LDS) + sampling + MFMA main conv ==========
// Block = 256 thr = 32 px. Phase 0: om GEMM -> s_om[216][36]. Phase 1: thread=(px,g)
// sampling from group-planar xg -> s_samp[px][k_new = g*36 + t*4 + c] bf16.
// Phase 2: wave=(mt,nt) MFMA (K=288 from LDS, k_new order matches wmA swizzle).
// MODE 0: NHWC bf16 no act. MODE 1: NHWC bf16 + lrelu. MODE 2: NCHW fp32 + lrelu.
template<int MODE>
__global__ __launch_bounds__(256)
void k_dcn_fused(const unsigned short* __restrict__ offn, // (B,H,W,32) bf16
                 const unsigned short* __restrict__ wswz, // om w B-frag swizzled
                 const float* __restrict__ om_b,          // [216]
                 const unsigned short* __restrict__ xg,   // (B,8,H,W,4) bf16 group-planar
                 const unsigned short* __restrict__ wmA,  // main w A-frag swizzled
                 const float* __restrict__ bias,          // [32]
                 float* __restrict__ outf,                // MODE 2
                 unsigned short* __restrict__ outb,       // MODE 0/1
                 int B, int H, int W) {
    const int ROW = 296;   // s_samp row stride shorts (288 + 8 pad; 592B, 16B-aligned)
    const int OMR = 36;    // s_om row stride (32 px + 4 pad) -> conflict-light stores
    __shared__ __align__(16) unsigned short s_om[216 * OMR];   // 15552 B
    __shared__ __align__(16) unsigned short s_samp[32 * ROW];  // 18944 B

    int tid = threadIdx.x;
    int lane = tid & 63;
    int wv = tid >> 6;
    int px0 = blockIdx.x * 32;

    // ---- phase 0: om GEMM into s_om ----
    {
        int n  = lane & 15;
        int kq = lane >> 4;

        int bmt[2], hmt[2], wmt[2];
#pragma unroll
        for (int mt = 0; mt < 2; ++mt) {
            int p0 = px0 + mt * 16;
            bmt[mt] = p0 / (H * W);
            hmt[mt] = (p0 / W) % H;
            wmt[mt] = p0 % W;
        }

        f32x4 acc[4][2];
#pragma unroll
        for (int i = 0; i < 4; ++i)
#pragma unroll
            for (int mt = 0; mt < 2; ++mt)
#pragma unroll
                for (int r = 0; r < 4; ++r) acc[i][mt][r] = 0.f;

#pragma unroll
        for (int t = 0; t < 9; ++t) {
            bf16x8 a[2];
#pragma unroll
            for (int mt = 0; mt < 2; ++mt) {
#pragma unroll
                for (int j = 0; j < 8; ++j) a[mt][j] = 0;
                int hy = hmt[mt] + t / 3 - 1;
                int wx = wmt[mt] + n + t % 3 - 1;
                if (hy >= 0 && hy < H && wx >= 0 && wx < W)
                    a[mt] = *(const bf16x8*)(offn + ((bmt[mt] * H + hy) * W + wx) * 32 + kq * 8);
            }
#pragma unroll
            for (int i = 0; i < 4; ++i) {
                int nt = wv * 4 + i;
                if (nt < 14) {
                    bf16x8 bf = *(const bf16x8*)(wswz + ((t * 14 + nt) * 64 + lane) * 8);
                    acc[i][0] = __builtin_amdgcn_mfma_f32_16x16x32_bf16(a[0], bf, acc[i][0], 0, 0, 0);
                    acc[i][1] = __builtin_amdgcn_mfma_f32_16x16x32_bf16(a[1], bf, acc[i][1], 0, 0, 0);
                }
            }
        }

#pragma unroll
        for (int i = 0; i < 4; ++i) {
            int nt = wv * 4 + i;
            if (nt < 14) {
                int ch = nt * 16 + n;
                if (ch < 216) {
#pragma unroll
                    for (int mt = 0; mt < 2; ++mt) {
                        uint2 v = make_uint2(pkbf(acc[i][mt][0], acc[i][mt][1]),
                                             pkbf(acc[i][mt][2], acc[i][mt][3]));
                        *(uint2*)(s_om + ch * OMR + mt * 16 + kq * 4) = v;
                    }
                }
            }
        }
    }
    __syncthreads();

    // ---- phase 1: sampling for (px, g) from group-planar xg ----
    {
        int px = tid & 31, g = tid >> 5;
        int idx = px0 + px;
        int w = idx % W;
        int h = (idx / W) % H;
        int b = idx / (W * H);

        float om27[27];
#pragma unroll
        for (int j = 0; j < 27; ++j)
            om27[j] = bf2f(s_om[(g * 27 + j) * OMR + px]) + om_b[g * 27 + j];

        const unsigned short* xb = xg + (size_t)(b * 8 + g) * (H * W) * 4;
        unsigned short* sdst = s_samp + px * ROW + g * 36;

#pragma unroll
        for (int k = 0; k < 9; ++k) {
            float mval = 1.f / (1.f + __expf(-om27[18 + k]));
            float py  = om27[k]     + (float)(h + k / 3 - 1);
            float pxx = om27[9 + k] + (float)(w + k % 3 - 1);
            float y0f = floorf(py), x0f = floorf(pxx);
            float dy = py - y0f, dx = pxx - x0f;
            int iy0 = (int)y0f, ix0 = (int)x0f;

            float wy0 = (iy0 >= 0 && iy0 < H) ? (1.f - dy) * mval : 0.f;
            float wy1 = (iy0 >= -1 && iy0 < H - 1) ? dy * mval : 0.f;

            // border handling via weight selection (bx covers both x-corners)
            float wa = 0.f, wb = 0.f;
            if (ix0 >= 0 && ix0 <= W - 2) { wa = 1.f - dx; wb = dx; }
            else if (ix0 == -1)           { wa = dx; }
            else if (ix0 == W - 1)        { wb = 1.f - dx; }

            int y0c = min(max(iy0, 0), H - 1);
            int y1c = min(max(iy0 + 1, 0), H - 1);
            int bx  = min(max(ix0, 0), W - 2);
            int o0 = (y0c * W + bx) * 4;
            int o1 = (y1c * W + bx) * 4;

            uint2 r0a = *(const uint2*)(xb + o0);        // row y0, x=bx,   ch0..3
            uint2 r0b = *(const uint2*)(xb + o0 + 4);    // row y0, x=bx+1
            uint2 r1a = *(const uint2*)(xb + o1);
            uint2 r1b = *(const uint2*)(xb + o1 + 4);

            f32x2 A01 = {bf_lo(r0a.x), bf_hi(r0a.x)};
            f32x2 A23 = {bf_lo(r0a.y), bf_hi(r0a.y)};
            f32x2 B01 = {bf_lo(r0b.x), bf_hi(r0b.x)};
            f32x2 B23 = {bf_lo(r0b.y), bf_hi(r0b.y)};
            f32x2 C01 = {bf_lo(r1a.x), bf_hi(r1a.x)};
            f32x2 C23 = {bf_lo(r1a.y), bf_hi(r1a.y)};
            f32x2 D01 = {bf_lo(r1b.x), bf_hi(r1b.x)};
            f32x2 D23 = {bf_lo(r1b.y), bf_hi(r1b.y)};

            f32x2 top01 = A01 * wa + B01 * wb;
            f32x2 top23 = A23 * wa + B23 * wb;
            f32x2 bot01 = C01 * wa + D01 * wb;
            f32x2 bot23 = C23 * wa + D23 * wb;
            f32x2 o01 = top01 * wy0 + bot01 * wy1;
            f32x2 o23 = top23 * wy0 + bot23 * wy1;

            *(uint2*)(sdst + k * 4) = make_uint2(pkbf(o01[0], o01[1]), pkbf(o23[0], o23[1]));
        }
    }
    __syncthreads();

    // ---- phase 2: wave (mt, nt) computes D[oc 16][px 16] ----
    int wsid = tid >> 6;
    int mt = wsid & 1, nt2 = wsid >> 1;

    f32x4 acc;
#pragma unroll
    for (int r = 0; r < 4; ++r) acc[r] = 0.f;

    const unsigned short* sb = s_samp + (nt2 * 16 + (lane & 15)) * ROW + (lane >> 4) * 8;
#pragma unroll
    for (int kc = 0; kc < 9; ++kc) {
        bf16x8 a   = *(const bf16x8*)(wmA + ((kc * 2 + mt) * 64 + lane) * 8);
        bf16x8 bfr = *(const bf16x8*)(sb + kc * 32);
        acc = __builtin_amdgcn_mfma_f32_16x16x32_bf16(a, bfr, acc, 0, 0, 0);
    }

    int pxg = px0 + nt2 * 16 + (lane & 15);
    int kq = lane >> 4;
    float4 bs = *(const float4*)(bias + mt * 16 + kq * 4);
    float v[4] = {acc[0] + bs.x, acc[1] + bs.y, acc[2] + bs.z, acc[3] + bs.w};
    if (MODE >= 1) {
#pragma unroll
        for (int r = 0; r < 4; ++r) v[r] = (v[r] >= 0.f) ? v[r] : 0.1f * v[r];
    }
    if (MODE == 2) {
        int w2 = pxg % W, h2 = (pxg / W) % H, b2 = pxg / (W * H);
#pragma unroll
        for (int r = 0; r < 4; ++r) {
            int oc = mt * 16 + kq * 4 + r;
            outf[((size_t)(b2 * 32 + oc) * H + h2) * W + w2] = v[r];
        }
    } else {
        uint2 sv = make_uint2(pkbf(v[0], v[1]), pkbf(v[2], v[3]));
        *(uint2*)(outb + (size_t)pxg * 32 + mt * 16 + kq * 4) = sv;
    }
}

// ================= exact 2x bilinear upsample, NHWC bf16 =================
__global__ void k_resize2x_nhwc(const unsigned short* __restrict__ in,
                                unsigned short* __restrict__ out,
                                int B, int Hin, int Win) {
    int Hout = Hin * 2, Wout = Win * 2;
    int i = blockIdx.x * 256 + threadIdx.x;     // (b,ho,wo,q) q=ch-octet
    int total = B * Hout * Wout * 4;
    if (i >= total) return;
    int q  = i & 3;
    int wo = (i >> 2) % Wout;
    int ho = (i >> 2) / Wout % Hout;
    int b  = (i >> 2) / (Wout * Hout);
    float fy = 0.5f * (float)ho - 0.25f;
    float fx = 0.5f * (float)wo - 0.25f;
    float y0f = floorf(fy), x0f = floorf(fx);
    float wy1 = fy - y0f, wx1 = fx - x0f;
    int y0 = max(0, min((int)y0f, Hin - 1));
    int y1 = max(0, min((int)y0f + 1, Hin - 1));
    int x0 = max(0, min((int)x0f, Win - 1));
    int x1 = max(0, min((int)x0f + 1, Win - 1));
    const unsigned short* base = in + ((size_t)b * Hin * Win) * 32 + q * 8;
    const uint4 u00 = *(const uint4*)(base + ((size_t)y0 * Win + x0) * 32);
    const uint4 u01 = *(const uint4*)(base + ((size_t)y0 * Win + x1) * 32);
    const uint4 u10 = *(const uint4*)(base + ((size_t)y1 * Win + x0) * 32);
    const uint4 u11 = *(const uint4*)(base + ((size_t)y1 * Win + x1) * 32);
    float c00 = (1.f - wy1) * (1.f - wx1), c01 = (1.f - wy1) * wx1;
    float c10 = wy1 * (1.f - wx1), c11 = wy1 * wx1;
    const unsigned int* p00 = (const unsigned int*)&u00;
    const unsigned int* p01 = (const unsigned int*)&u01;
    const unsigned int* p10 = (const unsigned int*)&u10;
    const unsigned int* p11 = (const unsigned int*)&u11;
    unsigned int packed[4];
#pragma unroll
    for (int d = 0; d < 4; ++d) {
        float lo = c00 * bf_lo(p00[d]) + c01 * bf_lo(p01[d]) +
                   c10 * bf_lo(p10[d]) + c11 * bf_lo(p11[d]);
        float hi = c00 * bf_hi(p00[d]) + c01 * bf_hi(p01[d]) +
                   c10 * bf_hi(p10[d]) + c11 * bf_hi(p11[d]);
        packed[d] = pkbf(lo, hi);
    }
    *(uint4*)(out + ((size_t)(b * Hout + ho) * Wout + wo) * 32 + q * 8) =
        make_uint4(packed[0], packed[1], packed[2], packed[3]);
}

extern "C" void kernel_launch(void* const* d_in, const int* in_sizes, int n_in,
                              void* d_out, int out_size, void* d_ws, size_t ws_size,
                              hipStream_t stream) {
    const float* L1_fea = (const float*)d_in[0];
    const float* L1_off = (const float*)d_in[1];
    const float* L2_off = (const float*)d_in[2];
    const float* L3_off = (const float*)d_in[3];
    const float* offset = (const float*)d_in[4];
    const float* w_l2c1 = (const float*)d_in[5];   const float* b_l2c1 = (const float*)d_in[6];
    const float* w_l2c2 = (const float*)d_in[7];   const float* b_l2c2 = (const float*)d_in[8];
    const float* w_l3c1 = (const float*)d_in[9];   const float* b_l3c1 = (const float*)d_in[10];
    const float* w_l3c2 = (const float*)d_in[11];  const float* b_l3c2 = (const float*)d_in[12];
    const float* w_l2fea = (const float*)d_in[13]; const float* b_l2fea = (const float*)d_in[14];
    const float* w_l1fea = (const float*)d_in[15]; const float* b_l1fea = (const float*)d_in[16];
    const float* l3_om_w = (const float*)d_in[17]; const float* l3_om_b = (const float*)d_in[18];
    const float* l3_w = (const float*)d_in[19];    const float* l3_b = (const float*)d_in[20];
    const float* l2_om_w = (const float*)d_in[21]; const float* l2_om_b = (const float*)d_in[22];
    const float* l2_w = (const float*)d_in[23];    const float* l2_b = (const float*)d_in[24];
    const float* l1_om_w = (const float*)d_in[25]; const float* l1_om_b = (const float*)d_in[26];
    const float* l1_w = (const float*)d_in[27];    const float* l1_b = (const float*)d_in[28];
    const float* cas_om_w = (const float*)d_in[29]; const float* cas_om_b = (const float*)d_in[30];
    const float* cas_w = (const float*)d_in[31];   const float* cas_b = (const float*)d_in[32];

    const int B = 4, H1 = 192, W1 = 192, H2 = 96, W2 = 96, H3 = 48, W3 = 48;
    const int HW1 = H1 * W1, HW2 = H2 * W2, HW3 = H3 * W3;

    char* ws = (char*)d_ws;
    size_t cur = 0;
    auto alloc = [&](size_t bytes) {
        char* p = ws + cur;
        cur += (bytes + 255) & ~(size_t)255;
        return p;
    };

    // weight buffers
    unsigned short* wA_l2c1  = (unsigned short*)alloc(9216 * 2);
    unsigned short* wA_l2c2  = (unsigned short*)alloc(9216 * 2);
    unsigned short* wA_l3c1  = (unsigned short*)alloc(9216 * 2);
    unsigned short* wA_l3c2  = (unsigned short*)alloc(9216 * 2);
    unsigned short* wA_l2fea = (unsigned short*)alloc(18432 * 2);
    unsigned short* wA_l1fea = (unsigned short*)alloc(18432 * 2);
    unsigned short* wmA_l3   = (unsigned short*)alloc(9216 * 2);
    unsigned short* wmA_l2   = (unsigned short*)alloc(9216 * 2);
    unsigned short* wmA_l1   = (unsigned short*)alloc(9216 * 2);
    unsigned short* wmA_cas  = (unsigned short*)alloc(9216 * 2);
    unsigned short* wswz_l3  = (unsigned short*)alloc(64512 * 2);
    unsigned short* wswz_l2  = (unsigned short*)alloc(64512 * 2);
    unsigned short* wswz_l1  = (unsigned short*)alloc(64512 * 2);
    unsigned short* wswz_cas = (unsigned short*)alloc(64512 * 2);

    // activations (NHWC bf16 + group-planar xg)
    unsigned short* offn_l3  = (unsigned short*)alloc((size_t)B * 32 * HW3 * 2);
    unsigned short* offn_l2  = (unsigned short*)alloc((size_t)B * 32 * HW2 * 2);
    unsigned short* offn_l1  = (unsigned short*)alloc((size_t)B * 32 * HW1 * 2);
    unsigned short* offn_cas = (unsigned short*)alloc((size_t)B * 32 * HW1 * 2);
    unsigned short* xn_l1    = (unsigned short*)alloc((size_t)B * 32 * HW1 * 2);
    unsigned short* L1g      = (unsigned short*)alloc((size_t)B * 32 * HW1 * 2);
    unsigned short* L2a      = (unsigned short*)alloc((size_t)B * 32 * HW2 * 2);
    unsigned short* L2n      = (unsigned short*)alloc((size_t)B * 32 * HW2 * 2);
    unsigned short* L2g      = (unsigned short*)alloc((size_t)B * 32 * HW2 * 2);
    unsigned short* L3a      = (unsigned short*)alloc((size_t)B * 32 * HW3 * 2);
    unsigned short* L3n      = (unsigned short*)alloc((size_t)B * 32 * HW3 * 2);
    unsigned short* L3g      = (unsigned short*)alloc((size_t)B * 32 * HW3 * 2);
    unsigned short* L3f      = (unsigned short*)alloc((size_t)B * 32 * HW3 * 2);
    unsigned short* L2f_pre  = (unsigned short*)alloc((size_t)B * 32 * HW2 * 2);
    unsigned short* L3u      = (unsigned short*)alloc((size_t)B * 32 * HW2 * 2);
    unsigned short* L2f      = (unsigned short*)alloc((size_t)B * 32 * HW2 * 2);
    unsigned short* L1f_pre  = (unsigned short*)alloc((size_t)B * 32 * HW1 * 2);
    unsigned short* L2u      = (unsigned short*)alloc((size_t)B * 32 * HW1 * 2);
    unsigned short* L1f      = (unsigned short*)alloc((size_t)B * 32 * HW1 * 2);
    unsigned short* L1fg     = (unsigned short*)alloc((size_t)B * 32 * HW1 * 2);

    // ---- merged weight prep (1 dispatch) ----
    {
        PrepP p;
        p.om_w[0] = l3_om_w; p.om_w[1] = l2_om_w; p.om_w[2] = l1_om_w; p.om_w[3] = cas_om_w;
        p.wswz[0] = wswz_l3; p.wswz[1] = wswz_l2; p.wswz[2] = wswz_l1; p.wswz[3] = wswz_cas;
        p.cw[0] = w_l2c1; p.cw[1] = w_l2c2; p.cw[2] = w_l3c1; p.cw[3] = w_l3c2;
        p.wA[0] = wA_l2c1; p.wA[1] = wA_l2c2; p.wA[2] = wA_l3c1; p.wA[3] = wA_l3c2;
        p.cw2[0] = w_l2fea; p.cw2[1] = w_l1fea;
        p.wA2[0] = wA_l2fea; p.wA2[1] = wA_l1fea;
        p.mw[0] = l3_w; p.mw[1] = l2_w; p.mw[2] = l1_w; p.mw[3] = cas_w;
        p.wmA[0] = wmA_l3; p.wmA[1] = wmA_l2; p.wmA[2] = wmA_l1; p.wmA[3] = wmA_cas;
        k_prep<<<dim3(CDIV(64512, 256), 14), 256, 0, stream>>>(p);
    }

    // ---- merged input conversions (1 dispatch) ----
    {
        CvtP p;
        p.src[0] = L1_off;  p.dst[0] = offn_l1;  p.HW[0] = HW1; p.mode[0] = 0;
        p.src[1] = offset;  p.dst[1] = offn_cas; p.HW[1] = HW1; p.mode[1] = 0;
        p.src[2] = L1_fea;  p.dst[2] = xn_l1;    p.HW[2] = HW1; p.mode[2] = 0;
        p.src[3] = L1_fea;  p.dst[3] = L1g;      p.HW[3] = HW1; p.mode[3] = 1;
        p.src[4] = L2_off;  p.dst[4] = offn_l2;  p.HW[4] = HW2; p.mode[4] = 0;
        p.src[5] = L3_off;  p.dst[5] = offn_l3;  p.HW[5] = HW3; p.mode[5] = 0;
        k_cvt<<<dim3(CDIV(B * 32 * HW1, 256), 6), 256, 0, stream>>>(p);
    }

    // ---- feature pyramid (MFMA convs, NHWC bf16) ----
    k_conv_mfma<3, 1, 2, true, false><<<CDIV(B * H2 * 2, 4), 256, 0, stream>>>(
        xn_l1, nullptr, wA_l2c1, b_l2c1, L2a, nullptr, B, H1, W1, H2, W2);
    k_conv_mfma<3, 1, 1, true, true><<<CDIV(B * H2 * 2, 4), 256, 0, stream>>>(
        L2a, nullptr, wA_l2c2, b_l2c2, L2n, L2g, B, H2, W2, H2, W2);
    k_conv_mfma<3, 1, 2, true, false><<<CDIV(B * H3 * 1, 4), 256, 0, stream>>>(
        L2n, nullptr, wA_l3c1, b_l3c1, L3a, nullptr, B, H2, W2, H3, W3);
    k_conv_mfma<3, 1, 1, true, true><<<CDIV(B * H3 * 1, 4), 256, 0, stream>>>(
        L3a, nullptr, wA_l3c2, b_l3c2, L3n, L3g, B, H3, W3, H3, W3);

    // ---- L3 dcn + lrelu ----
    k_dcn_fused<1><<<B * HW3 / 32, 256, 0, stream>>>(
        offn_l3, wswz_l3, l3_om_b, L3g, wmA_l3, l3_b, nullptr, L3f, B, H3, W3);

    // ---- L2 dcn, upsample L3f, fuse ----
    k_dcn_fused<0><<<B * HW2 / 32, 256, 0, stream>>>(
        offn_l2, wswz_l2, l2_om_b, L2g, wmA_l2, l2_b, nullptr, L2f_pre, B, H2, W2);
    k_resize2x_nhwc<<<CDIV(B * HW2 * 4, 256), 256, 0, stream>>>(L3f, L3u, B, H3, W3);
    k_conv_mfma<3, 2, 1, true, false><<<CDIV(B * H2 * 2, 4), 256, 0, stream>>>(
        L2f_pre, L3u, wA_l2fea, b_l2fea, L2f, nullptr, B, H2, W2, H2, W2);

    // ---- L1 dcn, upsample L2f, fuse (no act) ----
    k_dcn_fused<0><<<B * HW1 / 32, 256, 0, stream>>>(
        offn_l1, wswz_l1, l1_om_b, L1g, wmA_l1, l1_b, nullptr, L1f_pre, B, H1, W1);
    k_resize2x_nhwc<<<CDIV(B * HW1 * 4, 256), 256, 0, stream>>>(L2f, L2u, B, H2, W2);
    k_conv_mfma<4, 2, 1, false, true><<<CDIV(B * H1 * 3, 4), 256, 0, stream>>>(
        L1f_pre, L2u, wA_l1fea, b_l1fea, L1f, L1fg, B, H1, W1, H1, W1);

    // ---- cascading dcn + lrelu -> output (fp32 NCHW) ----
    k_dcn_fused<2><<<B * HW1 / 32, 256, 0, stream>>>(
        offn_cas, wswz_cas, cas_om_b, L1fg, wmA_cas, cas_b, (float*)d_out, nullptr, B, H1, W1);
}

// Round 9
// 526.073 us; speedup vs baseline: 1.1919x; 1.0128x over previous
//
#include <hip/hip_runtime.h>
#include <hip/hip_bf16.h>
#include <math.h>

#define NFC 32   // feature channels
#define DGC 8    // deformable groups (Cg = 4)

#define CDIV(a, b) (((a) + (b) - 1) / (b))

typedef __attribute__((ext_vector_type(8))) short bf16x8;
typedef __attribute__((ext_vector_type(4))) float f32x4;
typedef __attribute__((ext_vector_type(2))) float f32x2;
typedef uint4 __attribute__((aligned(8))) uint4a8;   // 16B load at 8B alignment

__device__ __forceinline__ unsigned short f2bf(float f) {
    unsigned int u = __float_as_uint(f);
    u += 0x7fffu + ((u >> 16) & 1u);          // RNE
    return (unsigned short)(u >> 16);
}
__device__ __forceinline__ float bf2f(unsigned short s) {
    return __uint_as_float((unsigned int)s << 16);
}
__device__ __forceinline__ float bf_lo(unsigned int u) { return __uint_as_float(u << 16); }
__device__ __forceinline__ float bf_hi(unsigned int u) { return __uint_as_float(u & 0xffff0000u); }

// packed f32x2 -> bf16x2 (v_cvt_pk_bf16_f32 on gfx950), RNE
__device__ __forceinline__ unsigned int pkbf(float a, float b) {
    __hip_bfloat162 h = __float22bfloat162_rn(make_float2(a, b));
    union { __hip_bfloat162 h2; unsigned int u; } cv;
    cv.h2 = h;
    return cv.u;
}

// ================= merged weight prep =================
struct PrepP {
    const float* om_w[4]; unsigned short* wswz[4];   // y 0..3
    const float* cw[4];   unsigned short* wA[4];     // y 4..7  (32-ic convs)
    const float* cw2[2];  unsigned short* wA2[2];    // y 8..9  (64-ic convs)
    const float* mw[4];   unsigned short* wmA[4];    // y 10..13
};

__global__ void k_prep(PrepP p) {
    int y = blockIdx.y;
    int i = blockIdx.x * 256 + threadIdx.x;
    if (y < 4) {
        // om weight (216,32,3,3) -> B-frag: wswz[((t*14+nt)*64+l)*8+j] = w[n][ic][t]
        if (i >= 9 * 14 * 64 * 8) return;
        int j  = i & 7;
        int l  = (i >> 3) & 63;
        int nt = (i >> 9) % 14;
        int t  = i / (14 * 512);
        int n  = nt * 16 + (l & 15);
        int ic = (l >> 4) * 8 + j;
        float v = (n < 216) ? p.om_w[y][(n * 32 + ic) * 9 + t] : 0.f;
        p.wswz[y][i] = f2bf(v);
    } else if (y < 8) {
        // conv w (32,32,3,3) -> A-frag k=(t): wA[((t*2+mt)*64+l)*8+j]
        if (i >= 9 * 1024) return;
        int idx = i;
        int j = idx & 7;   idx >>= 3;
        int l = idx & 63;  idx >>= 6;
        int mt = idx & 1;  idx >>= 1;
        int t = idx;
        int oc = mt * 16 + (l & 15);
        int ic = (l >> 4) * 8 + j;
        p.wA[y - 4][i] = f2bf(p.cw[y - 4][(oc * 32 + ic) * 9 + t]);
    } else if (y < 10) {
        // conv w (32,64,3,3) -> A-frag k=(t,ck)
        if (i >= 9 * 2 * 1024) return;
        int idx = i;
        int j = idx & 7;   idx >>= 3;
        int l = idx & 63;  idx >>= 6;
        int mt = idx & 1;  idx >>= 1;
        int ck = idx & 1;  idx >>= 1;
        int t = idx;
        int oc = mt * 16 + (l & 15);
        int ic = ck * 32 + (l >> 4) * 8 + j;
        p.wA2[y - 8][i] = f2bf(p.cw2[y - 8][(oc * 64 + ic) * 9 + t]);
    } else {
        // main dcn w (32,32,3,3) -> A-frag over k_new = g*36 + t*4 + c
        if (i >= 9216) return;
        int j  = i & 7;
        int l  = (i >> 3) & 63;
        int mt = (i >> 9) & 1;
        int kc = i >> 10;                          // 0..8
        int oc = mt * 16 + (l & 15);
        int k  = kc * 32 + (l >> 4) * 8 + j;       // k_new
        int g = k / 36, r = k % 36, t = r >> 2, c = r & 3;
        p.wmA[y - 10][i] = f2bf(p.mw[y - 10][(oc * 32 + g * 4 + c) * 9 + t]);
    }
}

// ================= merged input conversion =================
// mode 0: NCHW fp32 -> NHWC bf16 ; mode 1: NCHW fp32 -> group-planar xg (b,g,h,w,4) bf16
struct CvtP { const float* src[6]; unsigned short* dst[6]; int HW[6]; int mode[6]; };

__global__ void k_cvt(CvtP p) {
    int y = blockIdx.y;
    int HW = p.HW[y];
    int i = blockIdx.x * 256 + threadIdx.x;
    if (p.mode[y] == 0) {
        if (i >= 4 * HW * 32) return;
        int c = i & 31;
        int pxf = i >> 5;
        int b = pxf / HW;
        int hw = pxf % HW;
        p.dst[y][i] = f2bf(p.src[y][(b * 32 + c) * HW + hw]);
    } else {
        if (i >= 4 * 8 * HW) return;
        int hw = i % HW;
        int bg = i / HW;               // b*8+g
        int b = bg >> 3, g = bg & 7;
        const float* s = p.src[y] + (b * 32 + g * 4) * HW + hw;
        unsigned int lo = pkbf(s[0], s[HW]);
        unsigned int hi = pkbf(s[2 * HW], s[3 * HW]);
        *(uint2*)(p.dst[y] + (size_t)(bg * HW + hw) * 4) = make_uint2(lo, hi);
    }
}

// ================= MFMA 3x3 conv, NHWC bf16 in/out (+ optional xg copy) =================
template<int NT, int KC, int STRIDE, bool LRELU, bool XG>
__global__ __launch_bounds__(256)
void k_conv_mfma(const unsigned short* __restrict__ in1,  // NHWC bf16 32ch
                 const unsigned short* __restrict__ in2,  // NHWC bf16 32ch (KC=2) or null
                 const unsigned short* __restrict__ wA,   // A-fragment swizzled
                 const float* __restrict__ bias,          // [32]
                 unsigned short* __restrict__ out,        // NHWC bf16 32ch
                 unsigned short* __restrict__ outg,       // xg (b,g,h,w,4) if XG
                 int B, int Hin, int Win, int Hout, int Wout) {
    int wid  = (blockIdx.x * 256 + threadIdx.x) >> 6;
    int lane = threadIdx.x & 63;
    int strips = Wout / (16 * NT);
    if (wid >= B * Hout * strips) return;
    int st = wid % strips;
    int h  = (wid / strips) % Hout;
    int b  = wid / (strips * Hout);
    int px0 = st * 16 * NT;

    f32x4 acc[NT][2];
#pragma unroll
    for (int nt = 0; nt < NT; ++nt)
#pragma unroll
        for (int mt = 0; mt < 2; ++mt)
#pragma unroll
            for (int r = 0; r < 4; ++r) acc[nt][mt][r] = 0.f;

    int n  = lane & 15;
    int kq = lane >> 4;

#pragma unroll
    for (int t = 0; t < 9; ++t) {
        int hy = h * STRIDE + t / 3 - 1;
        if (hy < 0 || hy >= Hin) continue;
#pragma unroll
        for (int ck = 0; ck < KC; ++ck) {
            const unsigned short* rowp =
                ((KC == 2 && ck == 1) ? in2 : in1) + (size_t)(b * Hin + hy) * Win * 32;
            bf16x8 a0 = *(const bf16x8*)(wA + ((((t * KC + ck) * 2 + 0) * 64 + lane)) * 8);
            bf16x8 a1 = *(const bf16x8*)(wA + ((((t * KC + ck) * 2 + 1) * 64 + lane)) * 8);
#pragma unroll
            for (int nt = 0; nt < NT; ++nt) {
                int wx = (px0 + nt * 16 + n) * STRIDE + t % 3 - 1;
                bf16x8 bf;
#pragma unroll
                for (int j = 0; j < 8; ++j) bf[j] = 0;
                if (wx >= 0 && wx < Win)
                    bf = *(const bf16x8*)(rowp + wx * 32 + kq * 8);
                acc[nt][0] = __builtin_amdgcn_mfma_f32_16x16x32_bf16(a0, bf, acc[nt][0], 0, 0, 0);
                acc[nt][1] = __builtin_amdgcn_mfma_f32_16x16x32_bf16(a1, bf, acc[nt][1], 0, 0, 0);
            }
        }
    }

    size_t rowbase = ((size_t)(b * Hout + h) * Wout);
#pragma unroll
    for (int mt = 0; mt < 2; ++mt) {
        float4 bs = *(const float4*)(bias + mt * 16 + kq * 4);
#pragma unroll
        for (int nt = 0; nt < NT; ++nt) {
            int px = px0 + nt * 16 + n;
            float v0 = acc[nt][mt][0] + bs.x;
            float v1 = acc[nt][mt][1] + bs.y;
            float v2 = acc[nt][mt][2] + bs.z;
            float v3 = acc[nt][mt][3] + bs.w;
            if (LRELU) {
                v0 = (v0 >= 0.f) ? v0 : 0.1f * v0;
                v1 = (v1 >= 0.f) ? v1 : 0.1f * v1;
                v2 = (v2 >= 0.f) ? v2 : 0.1f * v2;
                v3 = (v3 >= 0.f) ? v3 : 0.1f * v3;
            }
            uint2 sv = make_uint2(pkbf(v0, v1), pkbf(v2, v3));
            *(uint2*)(out + (rowbase + px) * 32 + mt * 16 + kq * 4) = sv;
            if (XG) {
                int g = mt * 4 + kq;   // oc quad = one group's 4 channels
                *(uint2*)(outg + (((size_t)(b * 8 + g) * Hout + h) * Wout + px) * 4) = sv;
            }
        }
    }
}

// ========== fully fused DCN: om GEMM (LDS) + sampling + MFMA main conv ==========
// Block = 256 thr = 32 px. Phase 0: om GEMM -> s_om[216][36]. Phase 1: thread=(px,g)
// sampling from group-planar xg -> s_samp[px][k_new = g*36 + t*4 + c] bf16.
// Phase 2: wave=(mt,nt) MFMA (K=288 from LDS, k_new order matches wmA swizzle).
// MODE 0: NHWC bf16 no act. MODE 1: NHWC bf16 + lrelu. MODE 2: NCHW fp32 + lrelu.
template<int MODE>
__global__ __launch_bounds__(256)
void k_dcn_fused(const unsigned short* __restrict__ offn, // (B,H,W,32) bf16
                 const unsigned short* __restrict__ wswz, // om w B-frag swizzled
                 const float* __restrict__ om_b,          // [216]
                 const unsigned short* __restrict__ xg,   // (B,8,H,W,4) bf16 group-planar
                 const unsigned short* __restrict__ wmA,  // main w A-frag swizzled
                 const float* __restrict__ bias,          // [32]
                 float* __restrict__ outf,                // MODE 2
                 unsigned short* __restrict__ outb,       // MODE 0/1
                 int B, int H, int W) {
    const int ROW = 296;   // s_samp row stride shorts (288 + 8 pad; 592B, 16B-aligned)
    const int OMR = 36;    // s_om row stride (32 px + 4 pad) -> conflict-light stores
    __shared__ __align__(16) unsigned short s_om[216 * OMR];   // 15552 B
    __shared__ __align__(16) unsigned short s_samp[32 * ROW];  // 18944 B

    int tid = threadIdx.x;
    int lane = tid & 63;
    int wv = tid >> 6;
    int px0 = blockIdx.x * 32;

    // ---- phase 0: om GEMM into s_om ----
    {
        int n  = lane & 15;
        int kq = lane >> 4;

        int bmt[2], hmt[2], wmt[2];
#pragma unroll
        for (int mt = 0; mt < 2; ++mt) {
            int p0 = px0 + mt * 16;
            bmt[mt] = p0 / (H * W);
            hmt[mt] = (p0 / W) % H;
            wmt[mt] = p0 % W;
        }

        f32x4 acc[4][2];
#pragma unroll
        for (int i = 0; i < 4; ++i)
#pragma unroll
            for (int mt = 0; mt < 2; ++mt)
#pragma unroll
                for (int r = 0; r < 4; ++r) acc[i][mt][r] = 0.f;

#pragma unroll
        for (int t = 0; t < 9; ++t) {
            bf16x8 a[2];
#pragma unroll
            for (int mt = 0; mt < 2; ++mt) {
#pragma unroll
                for (int j = 0; j < 8; ++j) a[mt][j] = 0;
                int hy = hmt[mt] + t / 3 - 1;
                int wx = wmt[mt] + n + t % 3 - 1;
                if (hy >= 0 && hy < H && wx >= 0 && wx < W)
                    a[mt] = *(const bf16x8*)(offn + ((bmt[mt] * H + hy) * W + wx) * 32 + kq * 8);
            }
#pragma unroll
            for (int i = 0; i < 4; ++i) {
                int nt = wv * 4 + i;
                if (nt < 14) {
                    bf16x8 bf = *(const bf16x8*)(wswz + ((t * 14 + nt) * 64 + lane) * 8);
                    acc[i][0] = __builtin_amdgcn_mfma_f32_16x16x32_bf16(a[0], bf, acc[i][0], 0, 0, 0);
                    acc[i][1] = __builtin_amdgcn_mfma_f32_16x16x32_bf16(a[1], bf, acc[i][1], 0, 0, 0);
                }
            }
        }

#pragma unroll
        for (int i = 0; i < 4; ++i) {
            int nt = wv * 4 + i;
            if (nt < 14) {
                int ch = nt * 16 + n;
                if (ch < 216) {
#pragma unroll
                    for (int mt = 0; mt < 2; ++mt) {
                        uint2 v = make_uint2(pkbf(acc[i][mt][0], acc[i][mt][1]),
                                             pkbf(acc[i][mt][2], acc[i][mt][3]));
                        *(uint2*)(s_om + ch * OMR + mt * 16 + kq * 4) = v;
                    }
                }
            }
        }
    }
    __syncthreads();

    // ---- phase 1: sampling for (px, g) from group-planar xg ----
    {
        int px = tid & 31, g = tid >> 5;
        int idx = px0 + px;
        int w = idx % W;
        int h = (idx / W) % H;
        int b = idx / (W * H);

        float om27[27];
#pragma unroll
        for (int j = 0; j < 27; ++j)
            om27[j] = bf2f(s_om[(g * 27 + j) * OMR + px]) + om_b[g * 27 + j];

        const unsigned short* xb = xg + (size_t)(b * 8 + g) * (H * W) * 4;
        unsigned short* sdst = s_samp + px * ROW + g * 36;

        // pass A: per-tap addresses + weights (all live in registers)
        int o0s[9], o1s[9];
        float was[9], wbs[9], wy0s[9], wy1s[9];
#pragma unroll
        for (int k = 0; k < 9; ++k) {
            float mval = 1.f / (1.f + __expf(-om27[18 + k]));
            float py  = om27[k]     + (float)(h + k / 3 - 1);
            float pxx = om27[9 + k] + (float)(w + k % 3 - 1);
            float y0f = floorf(py), x0f = floorf(pxx);
            float dy = py - y0f, dx = pxx - x0f;
            int iy0 = (int)y0f, ix0 = (int)x0f;

            wy0s[k] = (iy0 >= 0 && iy0 < H) ? (1.f - dy) * mval : 0.f;
            wy1s[k] = (iy0 >= -1 && iy0 < H - 1) ? dy * mval : 0.f;

            float wa = 0.f, wb = 0.f;
            if (ix0 >= 0 && ix0 <= W - 2) { wa = 1.f - dx; wb = dx; }
            else if (ix0 == -1)           { wa = dx; }
            else if (ix0 == W - 1)        { wb = 1.f - dx; }
            was[k] = wa; wbs[k] = wb;

            int y0c = min(max(iy0, 0), H - 1);
            int y1c = min(max(iy0 + 1, 0), H - 1);
            int bx  = min(max(ix0, 0), W - 2);
            o0s[k] = (y0c * W + bx) * 4;
            o1s[k] = (y1c * W + bx) * 4;
        }

        // pass B: 16B gathers (both x-corners per load) + packed blend
#pragma unroll
        for (int k = 0; k < 9; ++k) {
            uint4 u0 = *(const uint4a8*)(xb + o0s[k]);   // row y0: ch0..3 @bx, @bx+1
            uint4 u1 = *(const uint4a8*)(xb + o1s[k]);   // row y1
            float wa = was[k], wb = wbs[k], wy0 = wy0s[k], wy1 = wy1s[k];

            f32x2 A01 = {bf_lo(u0.x), bf_hi(u0.x)};
            f32x2 A23 = {bf_lo(u0.y), bf_hi(u0.y)};
            f32x2 B01 = {bf_lo(u0.z), bf_hi(u0.z)};
            f32x2 B23 = {bf_lo(u0.w), bf_hi(u0.w)};
            f32x2 C01 = {bf_lo(u1.x), bf_hi(u1.x)};
            f32x2 C23 = {bf_lo(u1.y), bf_hi(u1.y)};
            f32x2 D01 = {bf_lo(u1.z), bf_hi(u1.z)};
            f32x2 D23 = {bf_lo(u1.w), bf_hi(u1.w)};

            f32x2 top01 = A01 * wa + B01 * wb;
            f32x2 top23 = A23 * wa + B23 * wb;
            f32x2 bot01 = C01 * wa + D01 * wb;
            f32x2 bot23 = C23 * wa + D23 * wb;
            f32x2 o01 = top01 * wy0 + bot01 * wy1;
            f32x2 o23 = top23 * wy0 + bot23 * wy1;

            *(uint2*)(sdst + k * 4) = make_uint2(pkbf(o01[0], o01[1]), pkbf(o23[0], o23[1]));
        }
    }
    __syncthreads();

    // ---- phase 2: wave (mt, nt) computes D[oc 16][px 16] ----
    int wsid = tid >> 6;
    int mt = wsid & 1, nt2 = wsid >> 1;

    f32x4 acc;
#pragma unroll
    for (int r = 0; r < 4; ++r) acc[r] = 0.f;

    const unsigned short* sb = s_samp + (nt2 * 16 + (lane & 15)) * ROW + (lane >> 4) * 8;
#pragma unroll
    for (int kc = 0; kc < 9; ++kc) {
        bf16x8 a   = *(const bf16x8*)(wmA + ((kc * 2 + mt) * 64 + lane) * 8);
        bf16x8 bfr = *(const bf16x8*)(sb + kc * 32);
        acc = __builtin_amdgcn_mfma_f32_16x16x32_bf16(a, bfr, acc, 0, 0, 0);
    }

    int pxg = px0 + nt2 * 16 + (lane & 15);
    int kq = lane >> 4;
    float4 bs = *(const float4*)(bias + mt * 16 + kq * 4);
    float v[4] = {acc[0] + bs.x, acc[1] + bs.y, acc[2] + bs.z, acc[3] + bs.w};
    if (MODE >= 1) {
#pragma unroll
        for (int r = 0; r < 4; ++r) v[r] = (v[r] >= 0.f) ? v[r] : 0.1f * v[r];
    }
    if (MODE == 2) {
        int w2 = pxg % W, h2 = (pxg / W) % H, b2 = pxg / (W * H);
#pragma unroll
        for (int r = 0; r < 4; ++r) {
            int oc = mt * 16 + kq * 4 + r;
            outf[((size_t)(b2 * 32 + oc) * H + h2) * W + w2] = v[r];
        }
    } else {
        uint2 sv = make_uint2(pkbf(v[0], v[1]), pkbf(v[2], v[3]));
        *(uint2*)(outb + (size_t)pxg * 32 + mt * 16 + kq * 4) = sv;
    }
}

// ================= exact 2x bilinear upsample, NHWC bf16 =================
__global__ void k_resize2x_nhwc(const unsigned short* __restrict__ in,
                                unsigned short* __restrict__ out,
                                int B, int Hin, int Win) {
    int Hout = Hin * 2, Wout = Win * 2;
    int i = blockIdx.x * 256 + threadIdx.x;     // (b,ho,wo,q) q=ch-octet
    int total = B * Hout * Wout * 4;
    if (i >= total) return;
    int q  = i & 3;
    int wo = (i >> 2) % Wout;
    int ho = (i >> 2) / Wout % Hout;
    int b  = (i >> 2) / (Wout * Hout);
    float fy = 0.5f * (float)ho - 0.25f;
    float fx = 0.5f * (float)wo - 0.25f;
    float y0f = floorf(fy), x0f = floorf(fx);
    float wy1 = fy - y0f, wx1 = fx - x0f;
    int y0 = max(0, min((int)y0f, Hin - 1));
    int y1 = max(0, min((int)y0f + 1, Hin - 1));
    int x0 = max(0, min((int)x0f, Win - 1));
    int x1 = max(0, min((int)x0f + 1, Win - 1));
    const unsigned short* base = in + ((size_t)b * Hin * Win) * 32 + q * 8;
    const uint4 u00 = *(const uint4*)(base + ((size_t)y0 * Win + x0) * 32);
    const uint4 u01 = *(const uint4*)(base + ((size_t)y0 * Win + x1) * 32);
    const uint4 u10 = *(const uint4*)(base + ((size_t)y1 * Win + x0) * 32);
    const uint4 u11 = *(const uint4*)(base + ((size_t)y1 * Win + x1) * 32);
    float c00 = (1.f - wy1) * (1.f - wx1), c01 = (1.f - wy1) * wx1;
    float c10 = wy1 * (1.f - wx1), c11 = wy1 * wx1;
    const unsigned int* p00 = (const unsigned int*)&u00;
    const unsigned int* p01 = (const unsigned int*)&u01;
    const unsigned int* p10 = (const unsigned int*)&u10;
    const unsigned int* p11 = (const unsigned int*)&u11;
    unsigned int packed[4];
#pragma unroll
    for (int d = 0; d < 4; ++d) {
        float lo = c00 * bf_lo(p00[d]) + c01 * bf_lo(p01[d]) +
                   c10 * bf_lo(p10[d]) + c11 * bf_lo(p11[d]);
        float hi = c00 * bf_hi(p00[d]) + c01 * bf_hi(p01[d]) +
                   c10 * bf_hi(p10[d]) + c11 * bf_hi(p11[d]);
        packed[d] = pkbf(lo, hi);
    }
    *(uint4*)(out + ((size_t)(b * Hout + ho) * Wout + wo) * 32 + q * 8) =
        make_uint4(packed[0], packed[1], packed[2], packed[3]);
}

extern "C" void kernel_launch(void* const* d_in, const int* in_sizes, int n_in,
                              void* d_out, int out_size, void* d_ws, size_t ws_size,
                              hipStream_t stream) {
    const float* L1_fea = (const float*)d_in[0];
    const float* L1_off = (const float*)d_in[1];
    const float* L2_off = (const float*)d_in[2];
    const float* L3_off = (const float*)d_in[3];
    const float* offset = (const float*)d_in[4];
    const float* w_l2c1 = (const float*)d_in[5];   const float* b_l2c1 = (const float*)d_in[6];
    const float* w_l2c2 = (const float*)d_in[7];   const float* b_l2c2 = (const float*)d_in[8];
    const float* w_l3c1 = (const float*)d_in[9];   const float* b_l3c1 = (const float*)d_in[10];
    const float* w_l3c2 = (const float*)d_in[11];  const float* b_l3c2 = (const float*)d_in[12];
    const float* w_l2fea = (const float*)d_in[13]; const float* b_l2fea = (const float*)d_in[14];
    const float* w_l1fea = (const float*)d_in[15]; const float* b_l1fea = (const float*)d_in[16];
    const float* l3_om_w = (const float*)d_in[17]; const float* l3_om_b = (const float*)d_in[18];
    const float* l3_w = (const float*)d_in[19];    const float* l3_b = (const float*)d_in[20];
    const float* l2_om_w = (const float*)d_in[21]; const float* l2_om_b = (const float*)d_in[22];
    const float* l2_w = (const float*)d_in[23];    const float* l2_b = (const float*)d_in[24];
    const float* l1_om_w = (const float*)d_in[25]; const float* l1_om_b = (const float*)d_in[26];
    const float* l1_w = (const float*)d_in[27];    const float* l1_b = (const float*)d_in[28];
    const float* cas_om_w = (const float*)d_in[29]; const float* cas_om_b = (const float*)d_in[30];
    const float* cas_w = (const float*)d_in[31];   const float* cas_b = (const float*)d_in[32];

    const int B = 4, H1 = 192, W1 = 192, H2 = 96, W2 = 96, H3 = 48, W3 = 48;
    const int HW1 = H1 * W1, HW2 = H2 * W2, HW3 = H3 * W3;

    char* ws = (char*)d_ws;
    size_t cur = 0;
    auto alloc = [&](size_t bytes) {
        char* p = ws + cur;
        cur += (bytes + 255) & ~(size_t)255;
        return p;
    };

    // weight buffers
    unsigned short* wA_l2c1  = (unsigned short*)alloc(9216 * 2);
    unsigned short* wA_l2c2  = (unsigned short*)alloc(9216 * 2);
    unsigned short* wA_l3c1  = (unsigned short*)alloc(9216 * 2);
    unsigned short* wA_l3c2  = (unsigned short*)alloc(9216 * 2);
    unsigned short* wA_l2fea = (unsigned short*)alloc(18432 * 2);
    unsigned short* wA_l1fea = (unsigned short*)alloc(18432 * 2);
    unsigned short* wmA_l3   = (unsigned short*)alloc(9216 * 2);
    unsigned short* wmA_l2   = (unsigned short*)alloc(9216 * 2);
    unsigned short* wmA_l1   = (unsigned short*)alloc(9216 * 2);
    unsigned short* wmA_cas  = (unsigned short*)alloc(9216 * 2);
    unsigned short* wswz_l3  = (unsigned short*)alloc(64512 * 2);
    unsigned short* wswz_l2  = (unsigned short*)alloc(64512 * 2);
    unsigned short* wswz_l1  = (unsigned short*)alloc(64512 * 2);
    unsigned short* wswz_cas = (unsigned short*)alloc(64512 * 2);

    // activations (NHWC bf16 + group-planar xg)
    unsigned short* offn_l3  = (unsigned short*)alloc((size_t)B * 32 * HW3 * 2);
    unsigned short* offn_l2  = (unsigned short*)alloc((size_t)B * 32 * HW2 * 2);
    unsigned short* offn_l1  = (unsigned short*)alloc((size_t)B * 32 * HW1 * 2);
    unsigned short* offn_cas = (unsigned short*)alloc((size_t)B * 32 * HW1 * 2);
    unsigned short* xn_l1    = (unsigned short*)alloc((size_t)B * 32 * HW1 * 2);
    unsigned short* L1g      = (unsigned short*)alloc((size_t)B * 32 * HW1 * 2);
    unsigned short* L2a      = (unsigned short*)alloc((size_t)B * 32 * HW2 * 2);
    unsigned short* L2n      = (unsigned short*)alloc((size_t)B * 32 * HW2 * 2);
    unsigned short* L2g      = (unsigned short*)alloc((size_t)B * 32 * HW2 * 2);
    unsigned short* L3a      = (unsigned short*)alloc((size_t)B * 32 * HW3 * 2);
    unsigned short* L3n      = (unsigned short*)alloc((size_t)B * 32 * HW3 * 2);
    unsigned short* L3g      = (unsigned short*)alloc((size_t)B * 32 * HW3 * 2);
    unsigned short* L3f      = (unsigned short*)alloc((size_t)B * 32 * HW3 * 2);
    unsigned short* L2f_pre  = (unsigned short*)alloc((size_t)B * 32 * HW2 * 2);
    unsigned short* L3u      = (unsigned short*)alloc((size_t)B * 32 * HW2 * 2);
    unsigned short* L2f      = (unsigned short*)alloc((size_t)B * 32 * HW2 * 2);
    unsigned short* L1f_pre  = (unsigned short*)alloc((size_t)B * 32 * HW1 * 2);
    unsigned short* L2u      = (unsigned short*)alloc((size_t)B * 32 * HW1 * 2);
    unsigned short* L1f      = (unsigned short*)alloc((size_t)B * 32 * HW1 * 2);
    unsigned short* L1fg     = (unsigned short*)alloc((size_t)B * 32 * HW1 * 2);

    // ---- merged weight prep (1 dispatch) ----
    {
        PrepP p;
        p.om_w[0] = l3_om_w; p.om_w[1] = l2_om_w; p.om_w[2] = l1_om_w; p.om_w[3] = cas_om_w;
        p.wswz[0] = wswz_l3; p.wswz[1] = wswz_l2; p.wswz[2] = wswz_l1; p.wswz[3] = wswz_cas;
        p.cw[0] = w_l2c1; p.cw[1] = w_l2c2; p.cw[2] = w_l3c1; p.cw[3] = w_l3c2;
        p.wA[0] = wA_l2c1; p.wA[1] = wA_l2c2; p.wA[2] = wA_l3c1; p.wA[3] = wA_l3c2;
        p.cw2[0] = w_l2fea; p.cw2[1] = w_l1fea;
        p.wA2[0] = wA_l2fea; p.wA2[1] = wA_l1fea;
        p.mw[0] = l3_w; p.mw[1] = l2_w; p.mw[2] = l1_w; p.mw[3] = cas_w;
        p.wmA[0] = wmA_l3; p.wmA[1] = wmA_l2; p.wmA[2] = wmA_l1; p.wmA[3] = wmA_cas;
        k_prep<<<dim3(CDIV(64512, 256), 14), 256, 0, stream>>>(p);
    }

    // ---- merged input conversions (1 dispatch) ----
    {
        CvtP p;
        p.src[0] = L1_off;  p.dst[0] = offn_l1;  p.HW[0] = HW1; p.mode[0] = 0;
        p.src[1] = offset;  p.dst[1] = offn_cas; p.HW[1] = HW1; p.mode[1] = 0;
        p.src[2] = L1_fea;  p.dst[2] = xn_l1;    p.HW[2] = HW1; p.mode[2] = 0;
        p.src[3] = L1_fea;  p.dst[3] = L1g;      p.HW[3] = HW1; p.mode[3] = 1;
        p.src[4] = L2_off;  p.dst[4] = offn_l2;  p.HW[4] = HW2; p.mode[4] = 0;
        p.src[5] = L3_off;  p.dst[5] = offn_l3;  p.HW[5] = HW3; p.mode[5] = 0;
        k_cvt<<<dim3(CDIV(B * 32 * HW1, 256), 6), 256, 0, stream>>>(p);
    }

    // ---- feature pyramid (MFMA convs, NHWC bf16; NT sized for occupancy) ----
    k_conv_mfma<1, 1, 2, true, false><<<CDIV(B * H2 * 6, 4), 256, 0, stream>>>(
        xn_l1, nullptr, wA_l2c1, b_l2c1, L2a, nullptr, B, H1, W1, H2, W2);
    k_conv_mfma<1, 1, 1, true, true><<<CDIV(B * H2 * 6, 4), 256, 0, stream>>>(
        L2a, nullptr, wA_l2c2, b_l2c2, L2n, L2g, B, H2, W2, H2, W2);
    k_conv_mfma<1, 1, 2, true, false><<<CDIV(B * H3 * 3, 4), 256, 0, stream>>>(
        L2n, nullptr, wA_l3c1, b_l3c1, L3a, nullptr, B, H2, W2, H3, W3);
    k_conv_mfma<1, 1, 1, true, true><<<CDIV(B * H3 * 3, 4), 256, 0, stream>>>(
        L3a, nullptr, wA_l3c2, b_l3c2, L3n, L3g, B, H3, W3, H3, W3);

    // ---- L3 dcn + lrelu ----
    k_dcn_fused<1><<<B * HW3 / 32, 256, 0, stream>>>(
        offn_l3, wswz_l3, l3_om_b, L3g, wmA_l3, l3_b, nullptr, L3f, B, H3, W3);

    // ---- L2 dcn, upsample L3f, fuse ----
    k_dcn_fused<0><<<B * HW2 / 32, 256, 0, stream>>>(
        offn_l2, wswz_l2, l2_om_b, L2g, wmA_l2, l2_b, nullptr, L2f_pre, B, H2, W2);
    k_resize2x_nhwc<<<CDIV(B * HW2 * 4, 256), 256, 0, stream>>>(L3f, L3u, B, H3, W3);
    k_conv_mfma<1, 2, 1, true, false><<<CDIV(B * H2 * 6, 4), 256, 0, stream>>>(
        L2f_pre, L3u, wA_l2fea, b_l2fea, L2f, nullptr, B, H2, W2, H2, W2);

    // ---- L1 dcn, upsample L2f, fuse (no act) ----
    k_dcn_fused<0><<<B * HW1 / 32, 256, 0, stream>>>(
        offn_l1, wswz_l1, l1_om_b, L1g, wmA_l1, l1_b, nullptr, L1f_pre, B, H1, W1);
    k_resize2x_nhwc<<<CDIV(B * HW1 * 4, 256), 256, 0, stream>>>(L2f, L2u, B, H2, W2);
    k_conv_mfma<2, 2, 1, false, true><<<CDIV(B * H1 * 6, 4), 256, 0, stream>>>(
        L1f_pre, L2u, wA_l1fea, b_l1fea, L1f, L1fg, B, H1, W1, H1, W1);

    // ---- cascading dcn + lrelu -> output (fp32 NCHW) ----
    k_dcn_fused<2><<<B * HW1 / 32, 256, 0, stream>>>(
        offn_cas, wswz_cas, cas_om_b, L1fg, wmA_cas, cas_b, (float*)d_out, nullptr, B, H1, W1);
}